// Round 6
// baseline (13.837 us; speedup 1.0000x reference)
//
#include <hip/hip_runtime.h>

// DepthLoss: loss = mean over {d>0} of |img[b,0,r,c] - d|, single f32 scalar.
// B=32, N=16384, H=768, W=1024. rdepth layout [B][N][3] = (row, col, d) f32.
//
// pass1: EPT=1 -> 524288 threads / 2048 blocks x 256 thr = 8 waves/SIMD
//        (full occupancy; ~32 in-flight vmem/SIMD for gather latency hiding).
//        XCD-chunked swizzle: vb = (bi%8)*256 + bi/8 -> XCD x gathers only
//        b-slices [4x,4x+4) (12 MB through its 4 MB L2). rdepth = 3 stride-12
//        NT scalar loads (wave spans 768B contiguous; lines reused via L1).
//        Per-block LDS reduce -> 2048 float2 partials.
// pass2: one 1024-thread block, fixed-order reduce -> deterministic.

#define TPB 256

constexpr int kN  = 16384;
constexpr int kH  = 768;
constexpr int kW  = 1024;
constexpr int kHW = kH * kW;

__global__ __launch_bounds__(TPB) void depthloss_pass1(
    const float* __restrict__ img,        // [B*H*W]
    const float* __restrict__ rd,         // [B*N*3]
    float2* __restrict__ partials,        // [gridDim.x]
    int nelem)
{
    // XCD-chunked swizzle (gridDim.x = 2048 = 8*256, exact -> bijective)
    int bi = blockIdx.x;
    int vb = (bi & 7) * 256 + (bi >> 3);

    int e = vb * TPB + threadIdx.x;       // one element per thread

    float loss = 0.f, cnt = 0.f;
    {
        int b = e >> 14;                  // kN = 2^14; uniform per block
        const float* base = img + (long)b * kHW;
        const float* p    = rd + (long)e * 3;

        float r = __builtin_nontemporal_load(p + 0);
        float c = __builtin_nontemporal_load(p + 1);
        float d = __builtin_nontemporal_load(p + 2);

        if (d > 0.f) {
            float v = base[((int)r << 10) + (int)c];   // kW = 1024
            loss = fabsf(v - d);
            cnt  = 1.f;
        }
    }

    // 64-lane wave reduction
    #pragma unroll
    for (int off = 32; off > 0; off >>= 1) {
        loss += __shfl_down(loss, off);
        cnt  += __shfl_down(cnt,  off);
    }

    __shared__ float2 lds[TPB / 64];
    int lane = threadIdx.x & 63;
    int wid  = threadIdx.x >> 6;
    if (lane == 0) lds[wid] = make_float2(loss, cnt);
    __syncthreads();

    if (threadIdx.x == 0) {
        float L = 0.f, C = 0.f;
        #pragma unroll
        for (int w = 0; w < TPB / 64; ++w) { L += lds[w].x; C += lds[w].y; }
        partials[blockIdx.x] = make_float2(L, C);
    }
}

__global__ __launch_bounds__(1024) void depthloss_pass2(
    const float2* __restrict__ partials, float* __restrict__ out, int np)
{
    int t = threadIdx.x;
    float L = 0.f, C = 0.f;
    for (int i = t; i < np; i += 1024) {   // fixed order -> deterministic
        float2 p = partials[i];
        L += p.x; C += p.y;
    }

    #pragma unroll
    for (int off = 32; off > 0; off >>= 1) {
        L += __shfl_down(L, off);
        C += __shfl_down(C, off);
    }

    __shared__ float2 lds[16];
    int lane = t & 63;
    int wid  = t >> 6;
    if (lane == 0) lds[wid] = make_float2(L, C);
    __syncthreads();

    if (t == 0) {
        float l = 0.f, c = 0.f;
        #pragma unroll
        for (int w = 0; w < 16; ++w) { l += lds[w].x; c += lds[w].y; }
        out[0] = (c > 0.f) ? (l / c) : 0.f;
    }
}

extern "C" void kernel_launch(void* const* d_in, const int* in_sizes, int n_in,
                              void* d_out, int out_size, void* d_ws, size_t ws_size,
                              hipStream_t stream) {
    const float* img    = (const float*)d_in[0];   // (B,1,H,W) f32
    const float* rdepth = (const float*)d_in[1];   // (B,N,3)  f32
    float* out = (float*)d_out;

    int nelem   = in_sizes[1] / 3;                  // 524288
    int nblocks = (nelem + TPB - 1) / TPB;          // 2048

    float2* partials = (float2*)d_ws;               // 16 KB

    depthloss_pass1<<<nblocks, TPB, 0, stream>>>(img, rdepth, partials, nelem);
    depthloss_pass2<<<1, 1024, 0, stream>>>(partials, out, nblocks);
}

// Round 7
// 12.793 us; speedup vs baseline: 1.0815x; 1.0815x over previous
//
#include <hip/hip_runtime.h>

// DepthLoss: loss = mean over {d>0} of |img[b,0,r,c] - d|, single f32 scalar.
// B=32, N=16384, H=768, W=1024. rdepth layout [B][N][3] = (row, col, d) f32.
//
// Best-measured configuration (R5, 12.96 us). Structure:
// pass1: 512 blocks x 256 thr, EPT=4. XCD-chunked block swizzle; rdepth read
//        as 3x float4 nontemporal (pure stream); all 4 gathers issued into
//        v[4] BEFORE any accumulate use -> 4-deep MLP per thread (this, not
//        locality, was the R4->R5 win). Per-block LDS reduce -> 512 partials.
// pass2: one 512-thread block, fixed-order reduce -> deterministic.
// Floor analysis: ~460K single-use random 64B line fetches, no reuse ->
// bound by L3 random-line service rate (~8 us) + 2-dispatch overhead (~4 us).

#define TPB 256
#define EPT 4      // 4 elems = 12 floats = 3x float4 (16B-aligned)

constexpr int kN  = 16384;
constexpr int kH  = 768;
constexpr int kW  = 1024;
constexpr int kHW = kH * kW;

typedef float floatx4 __attribute__((ext_vector_type(4)));  // native vec for nontemporal builtin

__global__ __launch_bounds__(TPB) void depthloss_pass1(
    const float* __restrict__ img,        // [B*H*W]
    const floatx4* __restrict__ rd4,      // B*N*3/4 float4s
    float2* __restrict__ partials,        // [gridDim.x]
    int nelem)
{
    // XCD-chunked swizzle (gridDim.x = 512 = 8*64, divides evenly -> bijective)
    int bi = blockIdx.x;
    int vb = (bi & 7) * 64 + (bi >> 3);

    int vtid = vb * TPB + threadIdx.x;
    int e0   = vtid * EPT;                // block covers 1024 contiguous elems

    float loss = 0.f, cnt = 0.f;
    if (e0 < nelem) {
        int b = e0 / kN;                  // uniform per block (1024 | 16384)
        const float* base = img + (long)b * kHW;

        floatx4 f0 = __builtin_nontemporal_load(&rd4[vtid * 3 + 0]);
        floatx4 f1 = __builtin_nontemporal_load(&rd4[vtid * 3 + 1]);
        floatx4 f2 = __builtin_nontemporal_load(&rd4[vtid * 3 + 2]);

        float r[4] = {f0.x, f0.w, f1.z, f2.y};
        float c[4] = {f0.y, f1.x, f1.w, f2.z};
        float d[4] = {f0.z, f1.y, f2.x, f2.w};

        // issue all 4 gathers (exec-masked) before accumulating: 4-deep MLP
        float v[4];
        #pragma unroll
        for (int k = 0; k < 4; ++k)
            v[k] = (d[k] > 0.f) ? base[(int)r[k] * kW + (int)c[k]] : 0.f;

        #pragma unroll
        for (int k = 0; k < 4; ++k) {
            if (d[k] > 0.f) { loss += fabsf(v[k] - d[k]); cnt += 1.f; }
        }
    }

    // 64-lane wave reduction
    #pragma unroll
    for (int off = 32; off > 0; off >>= 1) {
        loss += __shfl_down(loss, off);
        cnt  += __shfl_down(cnt,  off);
    }

    __shared__ float2 lds[TPB / 64];
    int lane = threadIdx.x & 63;
    int wid  = threadIdx.x >> 6;
    if (lane == 0) lds[wid] = make_float2(loss, cnt);
    __syncthreads();

    if (threadIdx.x == 0) {
        float L = 0.f, C = 0.f;
        #pragma unroll
        for (int w = 0; w < TPB / 64; ++w) { L += lds[w].x; C += lds[w].y; }
        partials[blockIdx.x] = make_float2(L, C);
    }
}

__global__ __launch_bounds__(512) void depthloss_pass2(
    const float2* __restrict__ partials, float* __restrict__ out, int np)
{
    int t = threadIdx.x;
    float L = 0.f, C = 0.f;
    if (t < np) { float2 p = partials[t]; L = p.x; C = p.y; }

    #pragma unroll
    for (int off = 32; off > 0; off >>= 1) {
        L += __shfl_down(L, off);
        C += __shfl_down(C, off);
    }

    __shared__ float2 lds[8];
    int lane = t & 63;
    int wid  = t >> 6;
    if (lane == 0) lds[wid] = make_float2(L, C);
    __syncthreads();

    if (t == 0) {
        float l = 0.f, c = 0.f;
        #pragma unroll
        for (int w = 0; w < 8; ++w) { l += lds[w].x; c += lds[w].y; }
        out[0] = (c > 0.f) ? (l / c) : 0.f;
    }
}

extern "C" void kernel_launch(void* const* d_in, const int* in_sizes, int n_in,
                              void* d_out, int out_size, void* d_ws, size_t ws_size,
                              hipStream_t stream) {
    const float* img    = (const float*)d_in[0];   // (B,1,H,W) f32
    const float* rdepth = (const float*)d_in[1];   // (B,N,3)  f32
    float* out = (float*)d_out;

    int nelem    = in_sizes[1] / 3;                 // 524288
    int nthreads = nelem / EPT;                     // 131072
    int nblocks  = (nthreads + TPB - 1) / TPB;      // 512

    float2* partials = (float2*)d_ws;               // 4 KB

    depthloss_pass1<<<nblocks, TPB, 0, stream>>>(
        img, (const floatx4*)rdepth, partials, nelem);
    depthloss_pass2<<<1, 512, 0, stream>>>(partials, out, nblocks);
}